// Round 3
// baseline (701.041 us; speedup 1.0000x reference)
//
#include <hip/hip_runtime.h>

// Problem constants
#define H_HEADS 16
#define KV_HEADS 8
#define DHEAD 128
#define HID 2048
#define NQ 1024
#define SCACHE 8192
#define CPOS 4096

typedef __attribute__((ext_vector_type(8))) __bf16 bf16x8;
typedef __attribute__((ext_vector_type(4))) float f32x4;
typedef unsigned short u16;
typedef unsigned int u32;

__device__ __forceinline__ u16 f2b(float f) {  // f32 -> bf16 bits, RNE
  u32 u = __float_as_uint(f);
  u += 0x7fffu + ((u >> 16) & 1u);
  return (u16)(u >> 16);
}
__device__ __forceinline__ float b2f(u16 b) { return __uint_as_float(((u32)b) << 16); }
__device__ __forceinline__ u32 pk2(u16 a, u16 b) { return (u32)a | ((u32)b << 16); }
__device__ __forceinline__ uint2 f4b4(float4 v) {  // 4 f32 -> 4 packed bf16
  uint2 o;
  o.x = pk2(f2b(v.x), f2b(v.y));
  o.y = pk2(f2b(v.z), f2b(v.w));
  return o;
}

union U4 { uint4 v; u16 u[8]; };

// GEMM1: qkv(4096 x 1024) bf16 = [Wq;Wk;Wv](4096 x 2048) f32 @ hidden(2048 x 1024) f32 + bias
// A rows are output channels (B^T form); B (hidden) is (K,N) native. 128x128 tile, 4 waves.
__global__ void __launch_bounds__(256) k_gemm_qkv(
    const float* __restrict__ Wq, const float* __restrict__ Wk, const float* __restrict__ Wv,
    const float* __restrict__ hid, u16* __restrict__ qkv,
    const float* __restrict__ bq, const float* __restrict__ bk, const float* __restrict__ bv) {
  __shared__ __align__(16) u16 lsA[128 * 32];
  __shared__ __align__(16) u16 lsB[32 * 140];  // (k, n) tile, stride 140
  int t = threadIdx.x;
  int m0 = blockIdx.x * 128, n0 = blockIdx.y * 128;
  const float* Abase;
  int mrel;
  if (m0 < 2048) { Abase = Wq; mrel = m0; }
  else if (m0 < 3072) { Abase = Wk; mrel = m0 - 2048; }
  else { Abase = Wv; mrel = m0 - 3072; }
  int lane = t & 63, wid = t >> 6;
  int quad = lane >> 4, l15 = lane & 15;
  int wr = wid >> 1, wc = wid & 1;
  f32x4 acc[4][4];
#pragma unroll
  for (int i = 0; i < 4; ++i)
#pragma unroll
    for (int j = 0; j < 4; ++j) acc[i][j] = (f32x4){0.f, 0.f, 0.f, 0.f};
  for (int kt = 0; kt < HID; kt += 32) {
    __syncthreads();
#pragma unroll
    for (int it = 0; it < 4; ++it) {  // A: 128 rows x 32 k  (1024 float4 chunks)
      int c = it * 256 + t;
      int row = c >> 3, ch = c & 7;
      float4 v = *(const float4*)(Abase + (size_t)(mrel + row) * HID + kt + ch * 4);
      *(uint2*)(lsA + row * 32 + ch * 4) = f4b4(v);
    }
#pragma unroll
    for (int it = 0; it < 4; ++it) {  // B: 32 k-rows x 128 n  (1024 float4 chunks)
      int c = it * 256 + t;
      int row = c >> 5, ch = c & 31;
      float4 v = *(const float4*)(hid + (size_t)(kt + row) * NQ + n0 + ch * 4);
      *(uint2*)(lsB + row * 140 + ch * 4) = f4b4(v);
    }
    __syncthreads();
    bf16x8 af[4], bfr[4];
#pragma unroll
    for (int i = 0; i < 4; ++i)
      af[i] = *(const bf16x8*)(lsA + (wr * 64 + i * 16 + l15) * 32 + quad * 8);
#pragma unroll
    for (int j4 = 0; j4 < 4; ++j4) {
      union { u16 u[8]; bf16x8 b; } cv;
#pragma unroll
      for (int j = 0; j < 8; ++j)
        cv.u[j] = lsB[(quad * 8 + j) * 140 + wc * 64 + j4 * 16 + l15];
      bfr[j4] = cv.b;
    }
#pragma unroll
    for (int i = 0; i < 4; ++i)
#pragma unroll
      for (int j = 0; j < 4; ++j)
        acc[i][j] = __builtin_amdgcn_mfma_f32_16x16x32_bf16(af[i], bfr[j], acc[i][j], 0, 0, 0);
  }
#pragma unroll
  for (int i = 0; i < 4; ++i) {
#pragma unroll
    for (int r = 0; r < 4; ++r) {
      int m = m0 + wr * 64 + i * 16 + quad * 4 + r;
      float bias = (m < 2048) ? bq[m] : ((m < 3072) ? bk[m - 2048] : bv[m - 3072]);
#pragma unroll
      for (int j = 0; j < 4; ++j) {
        int n = n0 + wc * 64 + j * 16 + l15;
        qkv[(size_t)m * NQ + n] = f2b(acc[i][j][r] + bias);
      }
    }
  }
}

// In-place RoPE on bf16 qkv rows [rowbase + hh*128, +128), 64 q-cols per block.
// out[dl] = x[dl]*cos - x[dl+64]*sin ; out[dl+64] = x[dl+64]*cos + x[dl]*sin
// (tables satisfy tab[q][d] == tab[q][d+64]). Optional 1/sqrt(128) scale (q only).
__global__ void __launch_bounds__(256) k_rope_ip(u16* __restrict__ qkv,
                                                 const float* __restrict__ cosb,
                                                 const float* __restrict__ sinb,
                                                 int rowbase, int applyScale) {
  int t = threadIdx.x;
  int base = rowbase + blockIdx.x * DHEAD;
  int dl = t & 63, qg = t >> 6;
  int c0 = blockIdx.y * 64 + qg * 16;
  u16* plow = qkv + (size_t)(base + dl) * NQ + c0;
  u16* phigh = plow + (size_t)64 * NQ;
  U4 lo0, lo1, hi0, hi1;
  lo0.v = *(uint4*)plow; lo1.v = *((uint4*)plow + 1);
  hi0.v = *(uint4*)phigh; hi1.v = *((uint4*)phigh + 1);
  float scale = applyScale ? 0.08838834764831845f : 1.0f;
  U4 ol0, ol1, oh0, oh1;
#pragma unroll
  for (int cc = 0; cc < 16; ++cc) {
    int q = c0 + cc;
    float cv = cosb[(size_t)q * DHEAD + dl];
    float sv = sinb[(size_t)q * DHEAD + dl];
    float a = b2f(cc < 8 ? lo0.u[cc] : lo1.u[cc - 8]);
    float b = b2f(cc < 8 ? hi0.u[cc] : hi1.u[cc - 8]);
    u16 rl = f2b((a * cv - b * sv) * scale);
    u16 rh = f2b((b * cv + a * sv) * scale);
    if (cc < 8) { ol0.u[cc] = rl; oh0.u[cc] = rh; }
    else { ol1.u[cc - 8] = rl; oh1.u[cc - 8] = rh; }
  }
  *(uint4*)plow = ol0.v; *((uint4*)plow + 1) = ol1.v;
  *(uint4*)phigh = oh0.v; *((uint4*)phigh + 1) = oh1.v;
}

// Flash attention: block = (head h, 64-query tile), 4 waves x 16 q-rows.
// Q from bf16 qkv (d-major). K/V: s<CPOS from f32 caches ((s,d) staging w/ convert),
// s>=CPOS from bf16 qkv k/v parts ((d,s) staging). Online softmax; out -> outT (q, h*D) bf16.
__global__ void __launch_bounds__(256) k_flash(const u16* __restrict__ qkv,
                                               const float* __restrict__ kcache,
                                               const float* __restrict__ vcache,
                                               u16* __restrict__ outT) {
  __shared__ __align__(16) u16 lsK[128 * 72];  // union: [64][136] (s,d) or [128][72] (d,s)
  __shared__ __align__(16) u16 lsV[128 * 72];
  __shared__ __align__(16) float lsP[4 * 16 * 68];  // per-wave 16 q x 64 s (pad 4)
  int t = threadIdx.x;
  int h = blockIdx.x, qt = blockIdx.y;
  int kv = h >> 1;
  int q0 = qt * 64;
  int lane = t & 63, wid = t >> 6;
  int quad = lane >> 4, l15 = lane & 15;
  int qw = q0 + wid * 16;
  // Q fragments from qkv rows [h*128, +128), col qw+l15 (scalar gathers, once)
  bf16x8 qf[4];
#pragma unroll
  for (int kc = 0; kc < 4; ++kc) {
    union { u16 u[8]; bf16x8 b; } cv;
#pragma unroll
    for (int j = 0; j < 8; ++j)
      cv.u[j] = qkv[(size_t)(h * DHEAD + kc * 32 + quad * 8 + j) * NQ + qw + l15];
    qf[kc] = cv.b;
  }
  f32x4 oacc[8];
#pragma unroll
  for (int f = 0; f < 8; ++f) oacc[f] = (f32x4){0.f, 0.f, 0.f, 0.f};
  float m_run[4], l_run[4];
#pragma unroll
  for (int r = 0; r < 4; ++r) { m_run[r] = -1e30f; l_run[r] = 0.f; }
  float* lsPw = lsP + wid * (16 * 68);
  int Svis = CPOS + q0 + 64;
  for (int s0 = 0; s0 < Svis; s0 += 64) {
    bool cached = (s0 < CPOS);
    if (cached) {
      // K,V: (s,d) layout [64][136], f32 -> bf16 convert while staging
#pragma unroll
      for (int it = 0; it < 8; ++it) {
        int c = it * 256 + t;  // 2048 float4 chunks per tensor
        int row = c >> 5, ch = c & 31;
        float4 kvv = *(const float4*)(kcache + ((size_t)kv * SCACHE + s0 + row) * DHEAD + ch * 4);
        *(uint2*)(lsK + row * 136 + ch * 4) = f4b4(kvv);
        float4 vvv = *(const float4*)(vcache + ((size_t)kv * SCACHE + s0 + row) * DHEAD + ch * 4);
        *(uint2*)(lsV + row * 136 + ch * 4) = f4b4(vvv);
      }
    } else {
      int sq = s0 - CPOS;
      // K,V: (d,s) layout [128][72], vectorized bf16 from qkv k/v parts (d-major native)
#pragma unroll
      for (int it = 0; it < 4; ++it) {
        int c = it * 256 + t;
        int row = c >> 3, ch = c & 7;
        *(uint4*)(lsK + row * 72 + ch * 8) =
            *(const uint4*)(qkv + (size_t)(HID + kv * DHEAD + row) * NQ + sq + ch * 8);
        *(uint4*)(lsV + row * 72 + ch * 8) =
            *(const uint4*)(qkv + (size_t)(3072 + kv * DHEAD + row) * NQ + sq + ch * 8);
      }
    }
    __syncthreads();
    // scores: 16q x 64s
    f32x4 sc[4];
#pragma unroll
    for (int js = 0; js < 4; ++js) {
      sc[js] = (f32x4){0.f, 0.f, 0.f, 0.f};
#pragma unroll
      for (int kc = 0; kc < 4; ++kc) {
        bf16x8 kf;
        if (cached) {
          kf = *(const bf16x8*)(lsK + (js * 16 + l15) * 136 + kc * 32 + quad * 8);
        } else {
          union { u16 u[8]; bf16x8 b; } cv;
#pragma unroll
          for (int j = 0; j < 8; ++j)
            cv.u[j] = lsK[(kc * 32 + quad * 8 + j) * 72 + js * 16 + l15];
          kf = cv.b;
        }
        sc[js] = __builtin_amdgcn_mfma_f32_16x16x32_bf16(qf[kc], kf, sc[js], 0, 0, 0);
      }
    }
    // causal mask + online softmax (q-row = quad*4+r; 16-lane reductions)
    float tmax[4];
#pragma unroll
    for (int r = 0; r < 4; ++r) {
      int lim = CPOS + qw + quad * 4 + r - s0;
#pragma unroll
      for (int js = 0; js < 4; ++js) {
        bool valid = (js * 16 + l15) <= lim;
        sc[js][r] = valid ? sc[js][r] : -1e30f;
      }
      float mx = fmaxf(fmaxf(sc[0][r], sc[1][r]), fmaxf(sc[2][r], sc[3][r]));
      mx = fmaxf(mx, __shfl_xor(mx, 1, 64));
      mx = fmaxf(mx, __shfl_xor(mx, 2, 64));
      mx = fmaxf(mx, __shfl_xor(mx, 4, 64));
      mx = fmaxf(mx, __shfl_xor(mx, 8, 64));
      tmax[r] = mx;
    }
    float alpha[4];
#pragma unroll
    for (int r = 0; r < 4; ++r) {
      float mnew = fmaxf(m_run[r], tmax[r]);
      alpha[r] = __expf(m_run[r] - mnew);
      m_run[r] = mnew;
      float rs = 0.f;
#pragma unroll
      for (int js = 0; js < 4; ++js) {
        float p = __expf(sc[js][r] - mnew);
        sc[js][r] = p;
        rs += p;
      }
      rs += __shfl_xor(rs, 1, 64);
      rs += __shfl_xor(rs, 2, 64);
      rs += __shfl_xor(rs, 4, 64);
      rs += __shfl_xor(rs, 8, 64);
      l_run[r] = l_run[r] * alpha[r] + rs;
    }
#pragma unroll
    for (int f = 0; f < 8; ++f)
#pragma unroll
      for (int r = 0; r < 4; ++r) oacc[f][r] *= alpha[r];
    // P: C-layout -> LDS -> A-layout (wave-private region; in-order LDS per wave)
#pragma unroll
    for (int js = 0; js < 4; ++js)
#pragma unroll
      for (int r = 0; r < 4; ++r)
        lsPw[(quad * 4 + r) * 68 + js * 16 + l15] = sc[js][r];
    bf16x8 pf[2];
#pragma unroll
    for (int ks = 0; ks < 2; ++ks) {
      const float* pr = lsPw + l15 * 68 + ks * 32 + quad * 8;
      f32x4 pa = *(const f32x4*)(pr);
      f32x4 pb = *(const f32x4*)(pr + 4);
      union { u16 u[8]; bf16x8 b; } cv;
#pragma unroll
      for (int j = 0; j < 4; ++j) { cv.u[j] = f2b(pa[j]); cv.u[4 + j] = f2b(pb[j]); }
      pf[ks] = cv.b;
    }
    // O += P * V
#pragma unroll
    for (int f = 0; f < 8; ++f) {
#pragma unroll
      for (int ks = 0; ks < 2; ++ks) {
        bf16x8 vf;
        if (cached) {
          union { u16 u[8]; bf16x8 b; } cv;
#pragma unroll
          for (int j = 0; j < 8; ++j)
            cv.u[j] = lsV[(ks * 32 + quad * 8 + j) * 136 + f * 16 + l15];
          vf = cv.b;
        } else {
          vf = *(const bf16x8*)(lsV + (f * 16 + l15) * 72 + ks * 32 + quad * 8);
        }
        oacc[f] = __builtin_amdgcn_mfma_f32_16x16x32_bf16(pf[ks], vf, oacc[f], 0, 0, 0);
      }
    }
    __syncthreads();
  }
  // epilogue: normalize, write outT (NQ, H*D) bf16 = B^T for the Wo GEMM
#pragma unroll
  for (int r = 0; r < 4; ++r) {
    float inv = 1.0f / l_run[r];
    int qg = qw + quad * 4 + r;
#pragma unroll
    for (int f = 0; f < 8; ++f)
      outT[(size_t)qg * HID + h * DHEAD + f * 16 + l15] = f2b(oacc[f][r] * inv);
  }
}

// GEMM2: out(2048 x 1024) f32 = Wo(2048 x 2048) f32 @ attn; B^T = outT (1024 x 2048) bf16.
__global__ void __launch_bounds__(256) k_gemm_bt(const float* __restrict__ A,
                                                 const u16* __restrict__ BT,
                                                 float* __restrict__ C) {
  __shared__ __align__(16) u16 lsA[128 * 32];
  __shared__ __align__(16) u16 lsB[128 * 32];
  int t = threadIdx.x;
  int m0 = blockIdx.x * 128, n0 = blockIdx.y * 128;
  int lane = t & 63, wid = t >> 6;
  int quad = lane >> 4, l15 = lane & 15;
  int wr = wid >> 1, wc = wid & 1;
  f32x4 acc[4][4];
#pragma unroll
  for (int i = 0; i < 4; ++i)
#pragma unroll
    for (int j = 0; j < 4; ++j) acc[i][j] = (f32x4){0.f, 0.f, 0.f, 0.f};
  for (int kt = 0; kt < HID; kt += 32) {
    __syncthreads();
#pragma unroll
    for (int it = 0; it < 4; ++it) {  // A: f32 -> bf16 staging (1024 float4 chunks)
      int c = it * 256 + t;
      int row = c >> 3, ch = c & 7;
      float4 v = *(const float4*)(A + (size_t)(m0 + row) * HID + kt + ch * 4);
      *(uint2*)(lsA + row * 32 + ch * 4) = f4b4(v);
    }
#pragma unroll
    for (int it = 0; it < 2; ++it) {  // B: bf16 native (512 uint4 chunks)
      int c = it * 256 + t;
      int row = c >> 2, ch = c & 3;
      *(uint4*)(lsB + row * 32 + ch * 8) =
          *(const uint4*)(BT + (size_t)(n0 + row) * HID + kt + ch * 8);
    }
    __syncthreads();
    bf16x8 af[4], bfr[4];
#pragma unroll
    for (int i = 0; i < 4; ++i)
      af[i] = *(const bf16x8*)(lsA + (wr * 64 + i * 16 + l15) * 32 + quad * 8);
#pragma unroll
    for (int j = 0; j < 4; ++j)
      bfr[j] = *(const bf16x8*)(lsB + (wc * 64 + j * 16 + l15) * 32 + quad * 8);
#pragma unroll
    for (int i = 0; i < 4; ++i)
#pragma unroll
      for (int j = 0; j < 4; ++j)
        acc[i][j] = __builtin_amdgcn_mfma_f32_16x16x32_bf16(af[i], bfr[j], acc[i][j], 0, 0, 0);
  }
#pragma unroll
  for (int i = 0; i < 4; ++i)
#pragma unroll
    for (int r = 0; r < 4; ++r) {
      int m = m0 + wr * 64 + i * 16 + quad * 4 + r;
#pragma unroll
      for (int j = 0; j < 4; ++j) {
        int n = n0 + wc * 64 + j * 16 + l15;
        C[(size_t)m * NQ + n] = acc[i][j][r];
      }
    }
}

extern "C" void kernel_launch(void* const* d_in, const int* in_sizes, int n_in,
                              void* d_out, int out_size, void* d_ws, size_t ws_size,
                              hipStream_t stream) {
  (void)in_sizes; (void)n_in; (void)out_size; (void)ws_size;
  const float* hidden = (const float*)d_in[0];
  const float* cosb = (const float*)d_in[1];
  const float* sinb = (const float*)d_in[2];
  // d_in[3] cos_t, d_in[4] sin_t, d_in[5] attention_mask: unused (recomputed analytically)
  const float* kcache = (const float*)d_in[6];
  const float* vcache = (const float*)d_in[7];
  const float* Wq = (const float*)d_in[8];
  const float* bq = (const float*)d_in[9];
  const float* Wk = (const float*)d_in[10];
  const float* bk = (const float*)d_in[11];
  const float* Wv = (const float*)d_in[12];
  const float* bv = (const float*)d_in[13];
  const float* Wo = (const float*)d_in[14];
  // d_in[15] cache_position = 4096 (fixed)

  char* ws = (char*)d_ws;
  u16* qkv = (u16*)(ws);              // 4096 x 1024 bf16 = 8,388,608 B
  u16* outT = (u16*)(ws + 8388608);   // 1024 x 2048 bf16 = 4,194,304 B  (total 12 MB)
  float* outb = (float*)d_out;

  k_gemm_qkv<<<dim3(32, 8), 256, 0, stream>>>(Wq, Wk, Wv, hidden, qkv, bq, bk, bv);
  k_rope_ip<<<dim3(16, 16), 256, 0, stream>>>(qkv, cosb, sinb, 0, 1);     // q, scaled
  k_rope_ip<<<dim3(8, 16), 256, 0, stream>>>(qkv, cosb, sinb, HID, 0);    // k
  k_flash<<<dim3(16, 16), 256, 0, stream>>>(qkv, kcache, vcache, outT);
  k_gemm_bt<<<dim3(16, 8), 256, 0, stream>>>(Wo, outT, outb);
}

// Round 4
// 585.879 us; speedup vs baseline: 1.1966x; 1.1966x over previous
//
#include <hip/hip_runtime.h>

// Problem constants
#define H_HEADS 16
#define KV_HEADS 8
#define DHEAD 128
#define HID 2048
#define NQ 1024
#define SCACHE 8192
#define CPOS 4096
#define SEFF 5120

typedef __attribute__((ext_vector_type(8))) __bf16 bf16x8;
typedef __attribute__((ext_vector_type(4))) float f32x4;
typedef unsigned short u16;
typedef unsigned int u32;

__device__ __forceinline__ u16 f2b(float f) {  // f32 -> bf16 bits, RNE
  u32 u = __float_as_uint(f);
  u += 0x7fffu + ((u >> 16) & 1u);
  return (u16)(u >> 16);
}
__device__ __forceinline__ float b2f(u16 b) { return __uint_as_float(((u32)b) << 16); }
__device__ __forceinline__ u32 pk2(u16 a, u16 b) { return (u32)a | ((u32)b << 16); }
__device__ __forceinline__ uint2 f4b4(float4 v) {
  uint2 o;
  o.x = pk2(f2b(v.x), f2b(v.y));
  o.y = pk2(f2b(v.z), f2b(v.w));
  return o;
}

union U4 { uint4 v; u16 u[8]; };

// hidden f32 (HID, NQ) -> hT bf16 (NQ, HID)   [B^T form for gemm1]
__global__ void __launch_bounds__(256) k_transpose_h(const float* __restrict__ hid,
                                                     u16* __restrict__ hT) {
  __shared__ __align__(16) float ls[64 * 68];
  int t = threadIdx.x;
  int c0 = blockIdx.x * 64, q0 = blockIdx.y * 64;
#pragma unroll
  for (int it = 0; it < 4; ++it) {  // 64 rows x 64 f32 = 1024 float4
    int c = it * 256 + t;
    int row = c >> 4, ch = c & 15;
    *(float4*)(ls + row * 68 + ch * 4) =
        *(const float4*)(hid + (size_t)(c0 + row) * NQ + q0 + ch * 4);
  }
  __syncthreads();
  int ql = t & 63, cch = t >> 6;
  u32 ob[8];
#pragma unroll
  for (int j = 0; j < 8; ++j)
    ob[j] = pk2(f2b(ls[(cch * 16 + 2 * j) * 68 + ql]), f2b(ls[(cch * 16 + 2 * j + 1) * 68 + ql]));
  uint4* dst = (uint4*)(hT + (size_t)(q0 + ql) * HID + c0 + cch * 16);
  dst[0] = make_uint4(ob[0], ob[1], ob[2], ob[3]);
  dst[1] = make_uint4(ob[4], ob[5], ob[6], ob[7]);
}

// vcache f32 (kv, s<CPOS, d) -> vT bf16 (kv, d, s)
__global__ void __launch_bounds__(256) k_prep_vT(const float* __restrict__ vc,
                                                 u16* __restrict__ vT) {
  __shared__ __align__(16) float ls[64 * 132];
  int t = threadIdx.x;
  int s0 = blockIdx.x * 64;
  int kv = blockIdx.y;
#pragma unroll
  for (int it = 0; it < 8; ++it) {  // 64 s x 128 d f32 = 2048 float4
    int c = it * 256 + t;
    int row = c >> 5, ch = c & 31;
    *(float4*)(ls + row * 132 + ch * 4) =
        *(const float4*)(vc + ((size_t)kv * SCACHE + s0 + row) * DHEAD + ch * 4);
  }
  __syncthreads();
  int d = t >> 1, sch = t & 1;
  u32 ob[16];
#pragma unroll
  for (int j = 0; j < 16; ++j)
    ob[j] = pk2(f2b(ls[(sch * 32 + 2 * j) * 132 + d]), f2b(ls[(sch * 32 + 2 * j + 1) * 132 + d]));
  uint4* dst = (uint4*)(vT + ((size_t)kv * DHEAD + d) * SEFF + s0 + sch * 32);
#pragma unroll
  for (int j = 0; j < 4; ++j)
    dst[j] = make_uint4(ob[4 * j], ob[4 * j + 1], ob[4 * j + 2], ob[4 * j + 3]);
}

// qkv v-part rows (d-major) -> vT s in [CPOS, SEFF)  (straight uint4 copy)
__global__ void __launch_bounds__(256) k_copy_vnew(const u16* __restrict__ qkv,
                                                   u16* __restrict__ vT) {
  int i = blockIdx.x * 256 + threadIdx.x;  // 131072 uint4 chunks
  int row = i >> 7, ch = i & 127;          // row = kv*128 + d
  *(uint4*)(vT + (size_t)row * SEFF + CPOS + ch * 8) =
      *(const uint4*)(qkv + (size_t)(3072 + row) * NQ + ch * 8);
}

// GEMM1: qkv(4096 x 1024) bf16 = [Wq;Wk;Wv](4096 x 2048) f32 @ hT^T + bias
__global__ void __launch_bounds__(256) k_gemm_qkv(
    const float* __restrict__ Wq, const float* __restrict__ Wk, const float* __restrict__ Wv,
    const u16* __restrict__ hT, u16* __restrict__ qkv,
    const float* __restrict__ bq, const float* __restrict__ bk, const float* __restrict__ bv) {
  __shared__ __align__(16) u16 lsA[128 * 32];
  __shared__ __align__(16) u16 lsB[128 * 32];
  int t = threadIdx.x;
  int m0 = blockIdx.x * 128, n0 = blockIdx.y * 128;
  const float* Abase;
  int mrel;
  if (m0 < 2048) { Abase = Wq; mrel = m0; }
  else if (m0 < 3072) { Abase = Wk; mrel = m0 - 2048; }
  else { Abase = Wv; mrel = m0 - 3072; }
  int lane = t & 63, wid = t >> 6;
  int quad = lane >> 4, l15 = lane & 15;
  int wr = wid >> 1, wc = wid & 1;
  f32x4 acc[4][4];
#pragma unroll
  for (int i = 0; i < 4; ++i)
#pragma unroll
    for (int j = 0; j < 4; ++j) acc[i][j] = (f32x4){0.f, 0.f, 0.f, 0.f};
  for (int kt = 0; kt < HID; kt += 32) {
    __syncthreads();
#pragma unroll
    for (int it = 0; it < 4; ++it) {  // A: f32 -> bf16 (1024 float4)
      int c = it * 256 + t;
      int row = c >> 3, ch = c & 7;
      float4 v = *(const float4*)(Abase + (size_t)(mrel + row) * HID + kt + ch * 4);
      *(uint2*)(lsA + row * 32 + ch * 4) = f4b4(v);
    }
#pragma unroll
    for (int it = 0; it < 2; ++it) {  // B: bf16 native (512 uint4)
      int c = it * 256 + t;
      int row = c >> 2, ch = c & 3;
      *(uint4*)(lsB + row * 32 + ch * 8) =
          *(const uint4*)(hT + (size_t)(n0 + row) * HID + kt + ch * 8);
    }
    __syncthreads();
    bf16x8 af[4], bfr[4];
#pragma unroll
    for (int i = 0; i < 4; ++i)
      af[i] = *(const bf16x8*)(lsA + (wr * 64 + i * 16 + l15) * 32 + quad * 8);
#pragma unroll
    for (int j = 0; j < 4; ++j)
      bfr[j] = *(const bf16x8*)(lsB + (wc * 64 + j * 16 + l15) * 32 + quad * 8);
#pragma unroll
    for (int i = 0; i < 4; ++i)
#pragma unroll
      for (int j = 0; j < 4; ++j)
        acc[i][j] = __builtin_amdgcn_mfma_f32_16x16x32_bf16(af[i], bfr[j], acc[i][j], 0, 0, 0);
  }
#pragma unroll
  for (int i = 0; i < 4; ++i) {
#pragma unroll
    for (int r = 0; r < 4; ++r) {
      int m = m0 + wr * 64 + i * 16 + quad * 4 + r;
      float bias = (m < 2048) ? bq[m] : ((m < 3072) ? bk[m - 2048] : bv[m - 3072]);
#pragma unroll
      for (int j = 0; j < 4; ++j) {
        int n = n0 + wc * 64 + j * 16 + l15;
        qkv[(size_t)m * NQ + n] = f2b(acc[i][j][r] + bias);
      }
    }
  }
}

// In-place RoPE on bf16 qkv rows, 64 q-cols per block (see round 3).
__global__ void __launch_bounds__(256) k_rope_ip(u16* __restrict__ qkv,
                                                 const float* __restrict__ cosb,
                                                 const float* __restrict__ sinb,
                                                 int rowbase, int applyScale) {
  int t = threadIdx.x;
  int base = rowbase + blockIdx.x * DHEAD;
  int dl = t & 63, qg = t >> 6;
  int c0 = blockIdx.y * 64 + qg * 16;
  u16* plow = qkv + (size_t)(base + dl) * NQ + c0;
  u16* phigh = plow + (size_t)64 * NQ;
  U4 lo0, lo1, hi0, hi1;
  lo0.v = *(uint4*)plow; lo1.v = *((uint4*)plow + 1);
  hi0.v = *(uint4*)phigh; hi1.v = *((uint4*)phigh + 1);
  float scale = applyScale ? 0.08838834764831845f : 1.0f;
  U4 ol0, ol1, oh0, oh1;
#pragma unroll
  for (int cc = 0; cc < 16; ++cc) {
    int q = c0 + cc;
    float cv = cosb[(size_t)q * DHEAD + dl];
    float sv = sinb[(size_t)q * DHEAD + dl];
    float a = b2f(cc < 8 ? lo0.u[cc] : lo1.u[cc - 8]);
    float b = b2f(cc < 8 ? hi0.u[cc] : hi1.u[cc - 8]);
    u16 rl = f2b((a * cv - b * sv) * scale);
    u16 rh = f2b((b * cv + a * sv) * scale);
    if (cc < 8) { ol0.u[cc] = rl; oh0.u[cc] = rh; }
    else { ol1.u[cc - 8] = rl; oh1.u[cc - 8] = rh; }
  }
  *(uint4*)plow = ol0.v; *((uint4*)plow + 1) = ol1.v;
  *(uint4*)phigh = oh0.v; *((uint4*)phigh + 1) = oh1.v;
}

// Flash attention, S-split flash-decoding: grid (h, qt, z=4 splits), 4 waves x 16 q-rows.
// Split z handles interleaved s-tiles s0 = z*64 + 256*i. Partial (U, m, l) -> ws.
__global__ void __launch_bounds__(256) k_flash(const u16* __restrict__ qkv,
                                               const float* __restrict__ kcache,
                                               const u16* __restrict__ vT,
                                               u16* __restrict__ po,
                                               float* __restrict__ pm,
                                               float* __restrict__ pl) {
  __shared__ __align__(16) u16 lsK[128 * 72];  // union: [64][136] (s,d) or [128][72] (d,s)
  __shared__ __align__(16) u16 lsV[128 * 72];  // always (d,s) [128][72] from vT
  __shared__ __align__(16) float lsP[4 * 16 * 68];
  int t = threadIdx.x;
  int h = blockIdx.x, qt = blockIdx.y, z = blockIdx.z;
  int kv = h >> 1;
  int q0 = qt * 64;
  int lane = t & 63, wid = t >> 6;
  int quad = lane >> 4, l15 = lane & 15;
  int qw = q0 + wid * 16;
  bf16x8 qf[4];
#pragma unroll
  for (int kc = 0; kc < 4; ++kc) {
    union { u16 u[8]; bf16x8 b; } cv;
#pragma unroll
    for (int j = 0; j < 8; ++j)
      cv.u[j] = qkv[(size_t)(h * DHEAD + kc * 32 + quad * 8 + j) * NQ + qw + l15];
    qf[kc] = cv.b;
  }
  f32x4 oacc[8];
#pragma unroll
  for (int f = 0; f < 8; ++f) oacc[f] = (f32x4){0.f, 0.f, 0.f, 0.f};
  float m_run[4], l_run[4];
#pragma unroll
  for (int r = 0; r < 4; ++r) { m_run[r] = -1e30f; l_run[r] = 0.f; }
  float* lsPw = lsP + wid * (16 * 68);
  int Svis = CPOS + q0 + 64;
  const u16* vbase = vT + (size_t)kv * DHEAD * SEFF;
  for (int s0 = z * 64; s0 < Svis; s0 += 256) {
    bool cached = (s0 < CPOS);
    if (cached) {
      // K: (s,d) [64][136], f32 -> bf16 convert while staging
#pragma unroll
      for (int it = 0; it < 8; ++it) {
        int c = it * 256 + t;
        int row = c >> 5, ch = c & 31;
        float4 kvv = *(const float4*)(kcache + ((size_t)kv * SCACHE + s0 + row) * DHEAD + ch * 4);
        *(uint2*)(lsK + row * 136 + ch * 4) = f4b4(kvv);
      }
    } else {
      int sq = s0 - CPOS;
      // K: (d,s) [128][72] from qkv k-part (d-major native)
#pragma unroll
      for (int it = 0; it < 4; ++it) {
        int c = it * 256 + t;
        int row = c >> 3, ch = c & 7;
        *(uint4*)(lsK + row * 72 + ch * 8) =
            *(const uint4*)(qkv + (size_t)(HID + kv * DHEAD + row) * NQ + sq + ch * 8);
      }
    }
    // V: (d,s) [128][72] from vT, both regions (vectorized)
#pragma unroll
    for (int it = 0; it < 4; ++it) {
      int c = it * 256 + t;
      int row = c >> 3, ch = c & 7;
      *(uint4*)(lsV + row * 72 + ch * 8) =
          *(const uint4*)(vbase + (size_t)row * SEFF + s0 + ch * 8);
    }
    __syncthreads();
    f32x4 sc[4];
#pragma unroll
    for (int js = 0; js < 4; ++js) {
      sc[js] = (f32x4){0.f, 0.f, 0.f, 0.f};
#pragma unroll
      for (int kc = 0; kc < 4; ++kc) {
        bf16x8 kf;
        if (cached) {
          kf = *(const bf16x8*)(lsK + (js * 16 + l15) * 136 + kc * 32 + quad * 8);
        } else {
          union { u16 u[8]; bf16x8 b; } cv;
#pragma unroll
          for (int j = 0; j < 8; ++j)
            cv.u[j] = lsK[(kc * 32 + quad * 8 + j) * 72 + js * 16 + l15];
          kf = cv.b;
        }
        sc[js] = __builtin_amdgcn_mfma_f32_16x16x32_bf16(qf[kc], kf, sc[js], 0, 0, 0);
      }
    }
    float tmax[4];
#pragma unroll
    for (int r = 0; r < 4; ++r) {
      int lim = CPOS + qw + quad * 4 + r - s0;
#pragma unroll
      for (int js = 0; js < 4; ++js) {
        bool valid = (js * 16 + l15) <= lim;
        sc[js][r] = valid ? sc[js][r] : -1e30f;
      }
      float mx = fmaxf(fmaxf(sc[0][r], sc[1][r]), fmaxf(sc[2][r], sc[3][r]));
      mx = fmaxf(mx, __shfl_xor(mx, 1, 64));
      mx = fmaxf(mx, __shfl_xor(mx, 2, 64));
      mx = fmaxf(mx, __shfl_xor(mx, 4, 64));
      mx = fmaxf(mx, __shfl_xor(mx, 8, 64));
      tmax[r] = mx;
    }
    float alpha[4];
#pragma unroll
    for (int r = 0; r < 4; ++r) {
      float mnew = fmaxf(m_run[r], tmax[r]);
      alpha[r] = __expf(m_run[r] - mnew);
      m_run[r] = mnew;
      float rs = 0.f;
#pragma unroll
      for (int js = 0; js < 4; ++js) {
        float p = __expf(sc[js][r] - mnew);
        sc[js][r] = p;
        rs += p;
      }
      rs += __shfl_xor(rs, 1, 64);
      rs += __shfl_xor(rs, 2, 64);
      rs += __shfl_xor(rs, 4, 64);
      rs += __shfl_xor(rs, 8, 64);
      l_run[r] = l_run[r] * alpha[r] + rs;
    }
#pragma unroll
    for (int f = 0; f < 8; ++f)
#pragma unroll
      for (int r = 0; r < 4; ++r) oacc[f][r] *= alpha[r];
    // P: C-layout -> LDS -> A-layout (wave-private)
#pragma unroll
    for (int js = 0; js < 4; ++js)
#pragma unroll
      for (int r = 0; r < 4; ++r)
        lsPw[(quad * 4 + r) * 68 + js * 16 + l15] = sc[js][r];
    bf16x8 pf[2];
#pragma unroll
    for (int ks = 0; ks < 2; ++ks) {
      const float* pr = lsPw + l15 * 68 + ks * 32 + quad * 8;
      f32x4 pa = *(const f32x4*)(pr);
      f32x4 pb = *(const f32x4*)(pr + 4);
      union { u16 u[8]; bf16x8 b; } cv;
#pragma unroll
      for (int j = 0; j < 4; ++j) { cv.u[j] = f2b(pa[j]); cv.u[4 + j] = f2b(pb[j]); }
      pf[ks] = cv.b;
    }
#pragma unroll
    for (int f = 0; f < 8; ++f) {
#pragma unroll
      for (int ks = 0; ks < 2; ++ks) {
        bf16x8 vf = *(const bf16x8*)(lsV + (f * 16 + l15) * 72 + ks * 32 + quad * 8);
        oacc[f] = __builtin_amdgcn_mfma_f32_16x16x32_bf16(pf[ks], vf, oacc[f], 0, 0, 0);
      }
    }
    __syncthreads();
  }
  // write partial (U unnormalized bf16, m, l) for split z
  int p = (h * 16 + qt) * 4 + z;
#pragma unroll
  for (int r = 0; r < 4; ++r) {
    int qloc = wid * 16 + quad * 4 + r;
    if (l15 == 0) {
      pm[(size_t)p * 64 + qloc] = m_run[r];
      pl[(size_t)p * 64 + qloc] = l_run[r];
    }
#pragma unroll
    for (int f = 0; f < 8; ++f)
      po[(size_t)p * 8192 + qloc * 128 + f * 16 + l15] = f2b(oacc[f][r]);
  }
}

// Combine 4 S-split partials -> outT (NQ, H*D) bf16
__global__ void __launch_bounds__(256) k_combine(const u16* __restrict__ po,
                                                 const float* __restrict__ pm,
                                                 const float* __restrict__ pl,
                                                 u16* __restrict__ outT) {
  int t = threadIdx.x;
  int h = blockIdx.x, qt = blockIdx.y;
  int p = h * 16 + qt, q0 = qt * 64;
  int qloc = t >> 2, dq = (t & 3) * 32;
  float m0 = pm[(size_t)(p * 4 + 0) * 64 + qloc];
  float m1 = pm[(size_t)(p * 4 + 1) * 64 + qloc];
  float m2 = pm[(size_t)(p * 4 + 2) * 64 + qloc];
  float m3 = pm[(size_t)(p * 4 + 3) * 64 + qloc];
  float M = fmaxf(fmaxf(m0, m1), fmaxf(m2, m3));
  float w[4] = {__expf(m0 - M), __expf(m1 - M), __expf(m2 - M), __expf(m3 - M)};
  float L = 0.f;
#pragma unroll
  for (int zz = 0; zz < 4; ++zz) L += w[zz] * pl[(size_t)(p * 4 + zz) * 64 + qloc];
  float acc[32];
#pragma unroll
  for (int e = 0; e < 32; ++e) acc[e] = 0.f;
#pragma unroll
  for (int zz = 0; zz < 4; ++zz) {
    const u16* src = po + (size_t)(p * 4 + zz) * 8192 + qloc * 128 + dq;
#pragma unroll
    for (int j = 0; j < 4; ++j) {
      U4 v;
      v.v = *(const uint4*)(src + j * 8);
#pragma unroll
      for (int e = 0; e < 8; ++e) acc[j * 8 + e] += w[zz] * b2f(v.u[e]);
    }
  }
  float inv = 1.0f / L;
  u16* dst = outT + (size_t)(q0 + qloc) * HID + h * DHEAD + dq;
#pragma unroll
  for (int j = 0; j < 4; ++j) {
    u32 ob[4];
#pragma unroll
    for (int e = 0; e < 4; ++e)
      ob[e] = pk2(f2b(acc[j * 8 + 2 * e] * inv), f2b(acc[j * 8 + 2 * e + 1] * inv));
    *(uint4*)(dst + j * 8) = make_uint4(ob[0], ob[1], ob[2], ob[3]);
  }
}

// GEMM2: out(2048 x 1024) f32 = Wo(2048 x 2048) f32 @ attn; B^T = outT bf16.
__global__ void __launch_bounds__(256) k_gemm_bt(const float* __restrict__ A,
                                                 const u16* __restrict__ BT,
                                                 float* __restrict__ C) {
  __shared__ __align__(16) u16 lsA[128 * 32];
  __shared__ __align__(16) u16 lsB[128 * 32];
  int t = threadIdx.x;
  int m0 = blockIdx.x * 128, n0 = blockIdx.y * 128;
  int lane = t & 63, wid = t >> 6;
  int quad = lane >> 4, l15 = lane & 15;
  int wr = wid >> 1, wc = wid & 1;
  f32x4 acc[4][4];
#pragma unroll
  for (int i = 0; i < 4; ++i)
#pragma unroll
    for (int j = 0; j < 4; ++j) acc[i][j] = (f32x4){0.f, 0.f, 0.f, 0.f};
  for (int kt = 0; kt < HID; kt += 32) {
    __syncthreads();
#pragma unroll
    for (int it = 0; it < 4; ++it) {
      int c = it * 256 + t;
      int row = c >> 3, ch = c & 7;
      float4 v = *(const float4*)(A + (size_t)(m0 + row) * HID + kt + ch * 4);
      *(uint2*)(lsA + row * 32 + ch * 4) = f4b4(v);
    }
#pragma unroll
    for (int it = 0; it < 2; ++it) {
      int c = it * 256 + t;
      int row = c >> 2, ch = c & 3;
      *(uint4*)(lsB + row * 32 + ch * 8) =
          *(const uint4*)(BT + (size_t)(n0 + row) * HID + kt + ch * 8);
    }
    __syncthreads();
    bf16x8 af[4], bfr[4];
#pragma unroll
    for (int i = 0; i < 4; ++i)
      af[i] = *(const bf16x8*)(lsA + (wr * 64 + i * 16 + l15) * 32 + quad * 8);
#pragma unroll
    for (int j = 0; j < 4; ++j)
      bfr[j] = *(const bf16x8*)(lsB + (wc * 64 + j * 16 + l15) * 32 + quad * 8);
#pragma unroll
    for (int i = 0; i < 4; ++i)
#pragma unroll
      for (int j = 0; j < 4; ++j)
        acc[i][j] = __builtin_amdgcn_mfma_f32_16x16x32_bf16(af[i], bfr[j], acc[i][j], 0, 0, 0);
  }
#pragma unroll
  for (int i = 0; i < 4; ++i)
#pragma unroll
    for (int r = 0; r < 4; ++r) {
      int m = m0 + wr * 64 + i * 16 + quad * 4 + r;
#pragma unroll
      for (int j = 0; j < 4; ++j) {
        int n = n0 + wc * 64 + j * 16 + l15;
        C[(size_t)m * NQ + n] = acc[i][j][r];
      }
    }
}

extern "C" void kernel_launch(void* const* d_in, const int* in_sizes, int n_in,
                              void* d_out, int out_size, void* d_ws, size_t ws_size,
                              hipStream_t stream) {
  (void)in_sizes; (void)n_in; (void)out_size; (void)ws_size;
  const float* hidden = (const float*)d_in[0];
  const float* cosb = (const float*)d_in[1];
  const float* sinb = (const float*)d_in[2];
  const float* kcache = (const float*)d_in[6];
  const float* vcache = (const float*)d_in[7];
  const float* Wq = (const float*)d_in[8];
  const float* bq = (const float*)d_in[9];
  const float* Wk = (const float*)d_in[10];
  const float* bk = (const float*)d_in[11];
  const float* Wv = (const float*)d_in[12];
  const float* bv = (const float*)d_in[13];
  const float* Wo = (const float*)d_in[14];

  char* ws = (char*)d_ws;
  u16* qkv = (u16*)(ws);                    // 4096x1024 bf16         =  8,388,608
  u16* outT = (u16*)(ws + 8388608);         // 1024x2048 bf16         =  4,194,304
  u16* hT = outT;                           // overlay: hT used before outT
  u16* vT = (u16*)(ws + 12582912);          // 8x128x5120 bf16        = 10,485,760
  u16* po = (u16*)(ws + 23068672);          // 1024 x 64x128 bf16     = 16,777,216
  float* pm = (float*)(ws + 39845888);      // 1024 x 64 f32          =    262,144
  float* pl = (float*)(ws + 40108032);      // 1024 x 64 f32          =    262,144
  float* outb = (float*)d_out;              // total ws: 40,370,176 B

  k_transpose_h<<<dim3(32, 16), 256, 0, stream>>>(hidden, hT);
  k_prep_vT<<<dim3(64, 8), 256, 0, stream>>>(vcache, vT);
  k_gemm_qkv<<<dim3(32, 8), 256, 0, stream>>>(Wq, Wk, Wv, hT, qkv, bq, bk, bv);
  k_rope_ip<<<dim3(16, 16), 256, 0, stream>>>(qkv, cosb, sinb, 0, 1);   // q, scaled
  k_rope_ip<<<dim3(8, 16), 256, 0, stream>>>(qkv, cosb, sinb, HID, 0);  // k
  k_copy_vnew<<<512, 256, 0, stream>>>(qkv, vT);
  k_flash<<<dim3(16, 16, 4), 256, 0, stream>>>(qkv, kcache, vT, po, pm, pl);
  k_combine<<<dim3(16, 16), 256, 0, stream>>>(po, pm, pl, outT);
  k_gemm_bt<<<dim3(16, 8), 256, 0, stream>>>(Wo, outT, outb);
}

// Round 5
// 417.422 us; speedup vs baseline: 1.6795x; 1.4036x over previous
//
#include <hip/hip_runtime.h>

// Problem constants
#define H_HEADS 16
#define KV_HEADS 8
#define DHEAD 128
#define HID 2048
#define NQ 1024
#define SCACHE 8192
#define CPOS 4096
#define SEFF 5120

typedef __attribute__((ext_vector_type(8))) __bf16 bf16x8;
typedef __attribute__((ext_vector_type(4))) float f32x4;
typedef unsigned short u16;
typedef unsigned int u32;

__device__ __forceinline__ u16 f2b(float f) {  // f32 -> bf16 bits, RNE
  u32 u = __float_as_uint(f);
  u += 0x7fffu + ((u >> 16) & 1u);
  return (u16)(u >> 16);
}
__device__ __forceinline__ float b2f(u16 b) { return __uint_as_float(((u32)b) << 16); }
__device__ __forceinline__ u32 pk2(u16 a, u16 b) { return (u32)a | ((u32)b << 16); }
__device__ __forceinline__ uint2 f4b4(float4 v) {
  uint2 o;
  o.x = pk2(f2b(v.x), f2b(v.y));
  o.y = pk2(f2b(v.z), f2b(v.w));
  return o;
}

union U4 { uint4 v; u16 u[8]; };

// Generic f32 -> bf16 streaming convert (n4 float4 chunks)
__global__ void __launch_bounds__(256) k_f32_to_bf16(const float* __restrict__ src,
                                                     u16* __restrict__ dst, int n4) {
  int i = blockIdx.x * 256 + threadIdx.x;
  if (i < n4) {
    float4 v = ((const float4*)src)[i];
    *(uint2*)(dst + (size_t)i * 4) = f4b4(v);
  }
}

// hidden f32 (HID, NQ) -> hT bf16 (NQ, HID)
__global__ void __launch_bounds__(256) k_transpose_h(const float* __restrict__ hid,
                                                     u16* __restrict__ hT) {
  __shared__ __align__(16) float ls[64 * 68];
  int t = threadIdx.x;
  int c0 = blockIdx.x * 64, q0 = blockIdx.y * 64;
#pragma unroll
  for (int it = 0; it < 4; ++it) {
    int c = it * 256 + t;
    int row = c >> 4, ch = c & 15;
    *(float4*)(ls + row * 68 + ch * 4) =
        *(const float4*)(hid + (size_t)(c0 + row) * NQ + q0 + ch * 4);
  }
  __syncthreads();
  int ql = t & 63, cch = t >> 6;
  u32 ob[8];
#pragma unroll
  for (int j = 0; j < 8; ++j)
    ob[j] = pk2(f2b(ls[(cch * 16 + 2 * j) * 68 + ql]), f2b(ls[(cch * 16 + 2 * j + 1) * 68 + ql]));
  uint4* dst = (uint4*)(hT + (size_t)(q0 + ql) * HID + c0 + cch * 16);
  dst[0] = make_uint4(ob[0], ob[1], ob[2], ob[3]);
  dst[1] = make_uint4(ob[4], ob[5], ob[6], ob[7]);
}

// vcache f32 (kv, s<CPOS, d) -> vT bf16 (kv, d, s)
__global__ void __launch_bounds__(256) k_prep_vT(const float* __restrict__ vc,
                                                 u16* __restrict__ vT) {
  __shared__ __align__(16) float ls[64 * 132];
  int t = threadIdx.x;
  int s0 = blockIdx.x * 64;
  int kv = blockIdx.y;
#pragma unroll
  for (int it = 0; it < 8; ++it) {
    int c = it * 256 + t;
    int row = c >> 5, ch = c & 31;
    *(float4*)(ls + row * 132 + ch * 4) =
        *(const float4*)(vc + ((size_t)kv * SCACHE + s0 + row) * DHEAD + ch * 4);
  }
  __syncthreads();
  int d = t >> 1, sch = t & 1;
  u32 ob[16];
#pragma unroll
  for (int j = 0; j < 16; ++j)
    ob[j] = pk2(f2b(ls[(sch * 32 + 2 * j) * 132 + d]), f2b(ls[(sch * 32 + 2 * j + 1) * 132 + d]));
  uint4* dst = (uint4*)(vT + ((size_t)kv * DHEAD + d) * SEFF + s0 + sch * 32);
#pragma unroll
  for (int j = 0; j < 4; ++j)
    dst[j] = make_uint4(ob[4 * j], ob[4 * j + 1], ob[4 * j + 2], ob[4 * j + 3]);
}

// kcache f32 (kv, s<CPOS, d) -> kb bf16 (kv, s, d)   [layout-preserving convert]
__global__ void __launch_bounds__(256) k_prep_kb(const float* __restrict__ kc,
                                                 u16* __restrict__ kb) {
  int i = blockIdx.x * 256 + threadIdx.x;  // 1,048,576 float4 chunks
  int kvi = i >> 17;                       // 131072 chunks per kv head
  int rem = i & 131071;
  float4 v = *(const float4*)(kc + (size_t)kvi * SCACHE * DHEAD + (size_t)rem * 4);
  *(uint2*)(kb + (size_t)kvi * SEFF * DHEAD + (size_t)rem * 4) = f4b4(v);
}

// qkv v-part rows (d-major) -> vT s in [CPOS, SEFF)
__global__ void __launch_bounds__(256) k_copy_vnew(const u16* __restrict__ qkv,
                                                   u16* __restrict__ vT) {
  int i = blockIdx.x * 256 + threadIdx.x;  // 131072 uint4 chunks
  int row = i >> 7, ch = i & 127;          // row = kv*128 + d
  *(uint4*)(vT + (size_t)row * SEFF + CPOS + ch * 8) =
      *(const uint4*)(qkv + (size_t)(3072 + row) * NQ + ch * 8);
}

// qkv k-part (d-major, post-RoPE) -> kb (kv, s=CPOS+q, d)  [transpose]
__global__ void __launch_bounds__(256) k_copy_knew(const u16* __restrict__ qkv,
                                                   u16* __restrict__ kb) {
  __shared__ __align__(16) u16 ls[128 * 68];
  int t = threadIdx.x;
  int kv = blockIdx.x, q0b = blockIdx.y * 64;
#pragma unroll
  for (int it = 0; it < 4; ++it) {  // 128 d-rows x 64 q = 1024 uint4
    int c = it * 256 + t;
    int row = c >> 3, ch = c & 7;
    *(uint4*)(ls + row * 68 + ch * 8) =
        *(const uint4*)(qkv + (size_t)(HID + kv * DHEAD + row) * NQ + q0b + ch * 8);
  }
  __syncthreads();
  int ql = t & 63, dc = t >> 6;
  u32 ob[16];
#pragma unroll
  for (int j = 0; j < 16; ++j)
    ob[j] = pk2(ls[(dc * 32 + 2 * j) * 68 + ql], ls[(dc * 32 + 2 * j + 1) * 68 + ql]);
  uint4* dst = (uint4*)(kb + ((size_t)kv * SEFF + CPOS + q0b + ql) * DHEAD + dc * 32);
#pragma unroll
  for (int j = 0; j < 4; ++j)
    dst[j] = make_uint4(ob[4 * j], ob[4 * j + 1], ob[4 * j + 2], ob[4 * j + 3]);
}

// GEMM1: qkv(4096 x 1024) bf16 = Wb(4096 x 2048) bf16 @ hT^T + bias
__global__ void __launch_bounds__(256) k_gemm_qkv(
    const u16* __restrict__ Wb, const u16* __restrict__ hT, u16* __restrict__ qkv,
    const float* __restrict__ bq, const float* __restrict__ bk, const float* __restrict__ bv) {
  __shared__ __align__(16) u16 lsA[128 * 32];
  __shared__ __align__(16) u16 lsB[128 * 32];
  int t = threadIdx.x;
  int m0 = blockIdx.x * 128, n0 = blockIdx.y * 128;
  const u16* Abase = Wb + (size_t)m0 * HID;
  int lane = t & 63, wid = t >> 6;
  int quad = lane >> 4, l15 = lane & 15;
  int wr = wid >> 1, wc = wid & 1;
  f32x4 acc[4][4];
#pragma unroll
  for (int i = 0; i < 4; ++i)
#pragma unroll
    for (int j = 0; j < 4; ++j) acc[i][j] = (f32x4){0.f, 0.f, 0.f, 0.f};
  for (int kt = 0; kt < HID; kt += 32) {
    __syncthreads();
#pragma unroll
    for (int it = 0; it < 2; ++it) {
      int c = it * 256 + t;
      int row = c >> 2, ch = c & 3;
      *(uint4*)(lsA + row * 32 + ch * 8) =
          *(const uint4*)(Abase + (size_t)row * HID + kt + ch * 8);
      *(uint4*)(lsB + row * 32 + ch * 8) =
          *(const uint4*)(hT + (size_t)(n0 + row) * HID + kt + ch * 8);
    }
    __syncthreads();
    bf16x8 af[4], bfr[4];
#pragma unroll
    for (int i = 0; i < 4; ++i)
      af[i] = *(const bf16x8*)(lsA + (wr * 64 + i * 16 + l15) * 32 + quad * 8);
#pragma unroll
    for (int j = 0; j < 4; ++j)
      bfr[j] = *(const bf16x8*)(lsB + (wc * 64 + j * 16 + l15) * 32 + quad * 8);
#pragma unroll
    for (int i = 0; i < 4; ++i)
#pragma unroll
      for (int j = 0; j < 4; ++j)
        acc[i][j] = __builtin_amdgcn_mfma_f32_16x16x32_bf16(af[i], bfr[j], acc[i][j], 0, 0, 0);
  }
#pragma unroll
  for (int i = 0; i < 4; ++i) {
#pragma unroll
    for (int r = 0; r < 4; ++r) {
      int m = m0 + wr * 64 + i * 16 + quad * 4 + r;
      float bias = (m < 2048) ? bq[m] : ((m < 3072) ? bk[m - 2048] : bv[m - 3072]);
#pragma unroll
      for (int j = 0; j < 4; ++j) {
        int n = n0 + wc * 64 + j * 16 + l15;
        qkv[(size_t)m * NQ + n] = f2b(acc[i][j][r] + bias);
      }
    }
  }
}

// In-place RoPE on bf16 qkv rows, 64 q-cols per block.
__global__ void __launch_bounds__(256) k_rope_ip(u16* __restrict__ qkv,
                                                 const float* __restrict__ cosb,
                                                 const float* __restrict__ sinb,
                                                 int rowbase, int applyScale) {
  int t = threadIdx.x;
  int base = rowbase + blockIdx.x * DHEAD;
  int dl = t & 63, qg = t >> 6;
  int c0 = blockIdx.y * 64 + qg * 16;
  u16* plow = qkv + (size_t)(base + dl) * NQ + c0;
  u16* phigh = plow + (size_t)64 * NQ;
  U4 lo0, lo1, hi0, hi1;
  lo0.v = *(uint4*)plow; lo1.v = *((uint4*)plow + 1);
  hi0.v = *(uint4*)phigh; hi1.v = *((uint4*)phigh + 1);
  float scale = applyScale ? 0.08838834764831845f : 1.0f;
  U4 ol0, ol1, oh0, oh1;
#pragma unroll
  for (int cc = 0; cc < 16; ++cc) {
    int q = c0 + cc;
    float cv = cosb[(size_t)q * DHEAD + dl];
    float sv = sinb[(size_t)q * DHEAD + dl];
    float a = b2f(cc < 8 ? lo0.u[cc] : lo1.u[cc - 8]);
    float b = b2f(cc < 8 ? hi0.u[cc] : hi1.u[cc - 8]);
    u16 rl = f2b((a * cv - b * sv) * scale);
    u16 rh = f2b((b * cv + a * sv) * scale);
    if (cc < 8) { ol0.u[cc] = rl; oh0.u[cc] = rh; }
    else { ol1.u[cc - 8] = rl; oh1.u[cc - 8] = rh; }
  }
  *(uint4*)plow = ol0.v; *((uint4*)plow + 1) = ol1.v;
  *(uint4*)phigh = oh0.v; *((uint4*)phigh + 1) = oh1.v;
}

// Flash attention, S-split: grid (h, qt, z=4), 4 waves x 16 q-rows.
// K from kb (kv,s,d) bf16; V from vT (kv,d,s) bf16. l via MFMA ones-row (oacc[8]).
__global__ void __launch_bounds__(256) k_flash(const u16* __restrict__ qkv,
                                               const u16* __restrict__ kb,
                                               const u16* __restrict__ vT,
                                               u16* __restrict__ po,
                                               float* __restrict__ pm,
                                               float* __restrict__ pl) {
  __shared__ __align__(16) u16 lsK[64 * 136];   // (s, d)
  __shared__ __align__(16) u16 lsV[144 * 68];   // (d, s); rows 128..143: ones/zeros
  __shared__ __align__(16) u16 lsP[4 * 16 * 68];
  int t = threadIdx.x;
  int h = blockIdx.x, qt = blockIdx.y, z = blockIdx.z;
  int kv = h >> 1;
  int q0 = qt * 64;
  int lane = t & 63, wid = t >> 6;
  int quad = lane >> 4, l15 = lane & 15;
  int qw = q0 + wid * 16;
  // ones-row init (row 128 = 1.0, rows 129..143 = 0) — before first barrier
  if (t < 128) {
    int row = 128 + (t >> 3), ch = t & 7;
    u32 fill = (row == 128) ? 0x3f803f80u : 0u;
    *(uint4*)(lsV + row * 68 + ch * 8) = make_uint4(fill, fill, fill, fill);
  }
  bf16x8 qf[4];
#pragma unroll
  for (int kc = 0; kc < 4; ++kc) {
    union { u16 u[8]; bf16x8 b; } cv;
#pragma unroll
    for (int j = 0; j < 8; ++j)
      cv.u[j] = qkv[(size_t)(h * DHEAD + kc * 32 + quad * 8 + j) * NQ + qw + l15];
    qf[kc] = cv.b;
  }
  f32x4 oacc[9];
#pragma unroll
  for (int f = 0; f < 9; ++f) oacc[f] = (f32x4){0.f, 0.f, 0.f, 0.f};
  float m_run[4];
#pragma unroll
  for (int r = 0; r < 4; ++r) m_run[r] = -1e30f;
  u16* lsPw = lsP + wid * (16 * 68);
  int Svis = CPOS + q0 + 64;
  const u16* kbase = kb + (size_t)kv * SEFF * DHEAD;
  const u16* vbase = vT + (size_t)kv * DHEAD * SEFF;
  for (int s0 = z * 64; s0 < Svis; s0 += 256) {
    // K: (s,d) 64x128 bf16, contiguous 16 KB; V: (d,s) 128x64
#pragma unroll
    for (int it = 0; it < 4; ++it) {
      int c = it * 256 + t;
      int rowK = c >> 4, chK = c & 15;
      *(uint4*)(lsK + rowK * 136 + chK * 8) =
          *(const uint4*)(kbase + (size_t)(s0 + rowK) * DHEAD + chK * 8);
      int rowV = c >> 3, chV = c & 7;
      *(uint4*)(lsV + rowV * 68 + chV * 8) =
          *(const uint4*)(vbase + (size_t)rowV * SEFF + s0 + chV * 8);
    }
    __syncthreads();
    f32x4 sc[4];
#pragma unroll
    for (int js = 0; js < 4; ++js) {
      sc[js] = (f32x4){0.f, 0.f, 0.f, 0.f};
#pragma unroll
      for (int kc = 0; kc < 4; ++kc) {
        bf16x8 kf = *(const bf16x8*)(lsK + (js * 16 + l15) * 136 + kc * 32 + quad * 8);
        sc[js] = __builtin_amdgcn_mfma_f32_16x16x32_bf16(qf[kc], kf, sc[js], 0, 0, 0);
      }
    }
    if (s0 + 63 > CPOS + qw) {  // boundary tile for this wave: apply causal mask
#pragma unroll
      for (int r = 0; r < 4; ++r) {
        int lim = CPOS + qw + quad * 4 + r - s0;
#pragma unroll
        for (int js = 0; js < 4; ++js) {
          bool valid = (js * 16 + l15) <= lim;
          sc[js][r] = valid ? sc[js][r] : -1e30f;
        }
      }
    }
    float alpha[4];
#pragma unroll
    for (int r = 0; r < 4; ++r) {
      float mx = fmaxf(fmaxf(sc[0][r], sc[1][r]), fmaxf(sc[2][r], sc[3][r]));
      mx = fmaxf(mx, __shfl_xor(mx, 1, 64));
      mx = fmaxf(mx, __shfl_xor(mx, 2, 64));
      mx = fmaxf(mx, __shfl_xor(mx, 4, 64));
      mx = fmaxf(mx, __shfl_xor(mx, 8, 64));
      float mnew = fmaxf(m_run[r], mx);
      alpha[r] = __expf(m_run[r] - mnew);
      m_run[r] = mnew;
#pragma unroll
      for (int js = 0; js < 4; ++js) {
        float p = __expf(sc[js][r] - mnew);
        sc[js][r] = p;
        lsPw[(quad * 4 + r) * 68 + js * 16 + l15] = f2b(p);
      }
    }
#pragma unroll
    for (int f = 0; f < 9; ++f)
#pragma unroll
      for (int r = 0; r < 4; ++r) oacc[f][r] *= alpha[r];
    bf16x8 pf[2];
#pragma unroll
    for (int ks = 0; ks < 2; ++ks)
      pf[ks] = *(const bf16x8*)(lsPw + l15 * 68 + ks * 32 + quad * 8);
    // O += P * V  (f=8 tile: ones row -> running l in oacc[8] col 0)
#pragma unroll
    for (int f = 0; f < 9; ++f) {
#pragma unroll
      for (int ks = 0; ks < 2; ++ks) {
        bf16x8 vf = *(const bf16x8*)(lsV + (f * 16 + l15) * 68 + ks * 32 + quad * 8);
        oacc[f] = __builtin_amdgcn_mfma_f32_16x16x32_bf16(pf[ks], vf, oacc[f], 0, 0, 0);
      }
    }
    __syncthreads();
  }
  int p = (h * 16 + qt) * 4 + z;
#pragma unroll
  for (int r = 0; r < 4; ++r) {
    int qloc = wid * 16 + quad * 4 + r;
    if (l15 == 0) {
      pm[(size_t)p * 64 + qloc] = m_run[r];
      pl[(size_t)p * 64 + qloc] = oacc[8][r];  // col 0 of ones-tile = sum_s P
    }
#pragma unroll
    for (int f = 0; f < 8; ++f)
      po[(size_t)p * 8192 + qloc * 128 + f * 16 + l15] = f2b(oacc[f][r]);
  }
}

// Combine 4 S-split partials -> outT (NQ, H*D) bf16
__global__ void __launch_bounds__(256) k_combine(const u16* __restrict__ po,
                                                 const float* __restrict__ pm,
                                                 const float* __restrict__ pl,
                                                 u16* __restrict__ outT) {
  int t = threadIdx.x;
  int h = blockIdx.x, qt = blockIdx.y;
  int p = h * 16 + qt, q0 = qt * 64;
  int qloc = t >> 2, dq = (t & 3) * 32;
  float m0 = pm[(size_t)(p * 4 + 0) * 64 + qloc];
  float m1 = pm[(size_t)(p * 4 + 1) * 64 + qloc];
  float m2 = pm[(size_t)(p * 4 + 2) * 64 + qloc];
  float m3 = pm[(size_t)(p * 4 + 3) * 64 + qloc];
  float M = fmaxf(fmaxf(m0, m1), fmaxf(m2, m3));
  float w[4] = {__expf(m0 - M), __expf(m1 - M), __expf(m2 - M), __expf(m3 - M)};
  float L = 0.f;
#pragma unroll
  for (int zz = 0; zz < 4; ++zz) L += w[zz] * pl[(size_t)(p * 4 + zz) * 64 + qloc];
  float acc[32];
#pragma unroll
  for (int e = 0; e < 32; ++e) acc[e] = 0.f;
#pragma unroll
  for (int zz = 0; zz < 4; ++zz) {
    const u16* src = po + (size_t)(p * 4 + zz) * 8192 + qloc * 128 + dq;
#pragma unroll
    for (int j = 0; j < 4; ++j) {
      U4 v;
      v.v = *(const uint4*)(src + j * 8);
#pragma unroll
      for (int e = 0; e < 8; ++e) acc[j * 8 + e] += w[zz] * b2f(v.u[e]);
    }
  }
  float inv = 1.0f / L;
  u16* dst = outT + (size_t)(q0 + qloc) * HID + h * DHEAD + dq;
#pragma unroll
  for (int j = 0; j < 4; ++j) {
    u32 ob[4];
#pragma unroll
    for (int e = 0; e < 4; ++e)
      ob[e] = pk2(f2b(acc[j * 8 + 2 * e] * inv), f2b(acc[j * 8 + 2 * e + 1] * inv));
    *(uint4*)(dst + j * 8) = make_uint4(ob[0], ob[1], ob[2], ob[3]);
  }
}

// GEMM2: out(2048 x 1024) f32 = Wob(2048 x 2048) bf16 @ attn; B^T = outT bf16.
__global__ void __launch_bounds__(256) k_gemm_bt(const u16* __restrict__ A,
                                                 const u16* __restrict__ BT,
                                                 float* __restrict__ C) {
  __shared__ __align__(16) u16 lsA[128 * 32];
  __shared__ __align__(16) u16 lsB[128 * 32];
  int t = threadIdx.x;
  int m0 = blockIdx.x * 128, n0 = blockIdx.y * 128;
  int lane = t & 63, wid = t >> 6;
  int quad = lane >> 4, l15 = lane & 15;
  int wr = wid >> 1, wc = wid & 1;
  f32x4 acc[4][4];
#pragma unroll
  for (int i = 0; i < 4; ++i)
#pragma unroll
    for (int j = 0; j < 4; ++j) acc[i][j] = (f32x4){0.f, 0.f, 0.f, 0.f};
  for (int kt = 0; kt < HID; kt += 32) {
    __syncthreads();
#pragma unroll
    for (int it = 0; it < 2; ++it) {
      int c = it * 256 + t;
      int row = c >> 2, ch = c & 3;
      *(uint4*)(lsA + row * 32 + ch * 8) =
          *(const uint4*)(A + (size_t)(m0 + row) * HID + kt + ch * 8);
      *(uint4*)(lsB + row * 32 + ch * 8) =
          *(const uint4*)(BT + (size_t)(n0 + row) * HID + kt + ch * 8);
    }
    __syncthreads();
    bf16x8 af[4], bfr[4];
#pragma unroll
    for (int i = 0; i < 4; ++i)
      af[i] = *(const bf16x8*)(lsA + (wr * 64 + i * 16 + l15) * 32 + quad * 8);
#pragma unroll
    for (int j = 0; j < 4; ++j)
      bfr[j] = *(const bf16x8*)(lsB + (wc * 64 + j * 16 + l15) * 32 + quad * 8);
#pragma unroll
    for (int i = 0; i < 4; ++i)
#pragma unroll
      for (int j = 0; j < 4; ++j)
        acc[i][j] = __builtin_amdgcn_mfma_f32_16x16x32_bf16(af[i], bfr[j], acc[i][j], 0, 0, 0);
  }
#pragma unroll
  for (int i = 0; i < 4; ++i)
#pragma unroll
    for (int r = 0; r < 4; ++r) {
      int m = m0 + wr * 64 + i * 16 + quad * 4 + r;
#pragma unroll
      for (int j = 0; j < 4; ++j) {
        int n = n0 + wc * 64 + j * 16 + l15;
        C[(size_t)m * NQ + n] = acc[i][j][r];
      }
    }
}

extern "C" void kernel_launch(void* const* d_in, const int* in_sizes, int n_in,
                              void* d_out, int out_size, void* d_ws, size_t ws_size,
                              hipStream_t stream) {
  (void)in_sizes; (void)n_in; (void)out_size; (void)ws_size;
  const float* hidden = (const float*)d_in[0];
  const float* cosb = (const float*)d_in[1];
  const float* sinb = (const float*)d_in[2];
  const float* kcache = (const float*)d_in[6];
  const float* vcache = (const float*)d_in[7];
  const float* Wq = (const float*)d_in[8];
  const float* bq = (const float*)d_in[9];
  const float* Wk = (const float*)d_in[10];
  const float* bk = (const float*)d_in[11];
  const float* Wv = (const float*)d_in[12];
  const float* bv = (const float*)d_in[13];
  const float* Wo = (const float*)d_in[14];

  char* ws = (char*)d_ws;
  u16* qkv = (u16*)(ws);                    // 4096x1024 bf16     =  8,388,608
  u16* outT = (u16*)(ws + 8388608);         // 1024x2048 bf16     =  4,194,304
  u16* hT = outT;                           // overlay: hT dead before outT written
  u16* vT = (u16*)(ws + 12582912);          // 8x128x5120 bf16    = 10,485,760
  u16* Wob = vT;                            // overlay: vT dead after flash
  u16* kb = (u16*)(ws + 23068672);          // 8x5120x128 bf16    = 10,485,760
  u16* po = (u16*)(ws + 33554432);          // 1024x64x128 bf16   = 16,777,216
  u16* Wb = po;                             // overlay: Wb dead before po written
  float* pm = (float*)(ws + 50331648);      // 1024x64 f32        =    262,144
  float* pl = (float*)(ws + 50593792);      // 1024x64 f32        =    262,144
  float* outb = (float*)d_out;              // total ws: 50,855,936 B

  k_f32_to_bf16<<<4096, 256, 0, stream>>>(Wq, Wb, 1048576);
  k_f32_to_bf16<<<2048, 256, 0, stream>>>(Wk, Wb + 2048 * 2048, 524288);
  k_f32_to_bf16<<<2048, 256, 0, stream>>>(Wv, Wb + 3072 * 2048, 524288);
  k_transpose_h<<<dim3(32, 16), 256, 0, stream>>>(hidden, hT);
  k_prep_vT<<<dim3(64, 8), 256, 0, stream>>>(vcache, vT);
  k_prep_kb<<<4096, 256, 0, stream>>>(kcache, kb);
  k_gemm_qkv<<<dim3(32, 8), 256, 0, stream>>>(Wb, hT, qkv, bq, bk, bv);
  k_rope_ip<<<dim3(16, 16), 256, 0, stream>>>(qkv, cosb, sinb, 0, 1);   // q, scaled
  k_rope_ip<<<dim3(8, 16), 256, 0, stream>>>(qkv, cosb, sinb, HID, 0);  // k
  k_copy_vnew<<<512, 256, 0, stream>>>(qkv, vT);
  k_copy_knew<<<dim3(8, 16), 256, 0, stream>>>(qkv, kb);
  k_flash<<<dim3(16, 16, 4), 256, 0, stream>>>(qkv, kb, vT, po, pm, pl);
  k_combine<<<dim3(16, 16), 256, 0, stream>>>(po, pm, pl, outT);
  k_f32_to_bf16<<<4096, 256, 0, stream>>>(Wo, Wob, 1048576);
  k_gemm_bt<<<dim3(16, 8), 256, 0, stream>>>(Wob, outT, outb);
}